// Round 1
// baseline (197.017 us; speedup 1.0000x reference)
//
#include <hip/hip_runtime.h>

#define N_NODES 1048576
#define THR 16.0f
#define PPT 8   // pairs per thread: 16 cell gathers in flight per thread

typedef int int4v __attribute__((ext_vector_type(4)));

// cells of width 16: |dx| < 16 is impossible when |cellx_s - cellx_d| >= 2,
// because cx in cell c means cx in [16c, 16c+16), so celldiff k>=2 implies
// |dx| > 16(k-1) >= 16. Prefilter is exactly conservative (no false rejects)
// since cells are computed from the SAME stored cx/cy the exact path gathers.
__global__ void centers_kernel(const float* __restrict__ pos,
                               const float* __restrict__ nsx,
                               const float* __restrict__ nsy,
                               float* __restrict__ cx, float* __restrict__ cy,
                               unsigned short* __restrict__ cell,
                               float* __restrict__ ex, float* __restrict__ ey,
                               float* __restrict__ out) {
    int i = blockIdx.x * blockDim.x + threadIdx.x;
    if (i < N_NODES) {
        float x = pos[i] + 0.5f * nsx[i];
        float y = pos[N_NODES + i] + 0.5f * nsy[i];
        cx[i] = x;
        cy[i] = y;
        // x,y >= 0 and < ~1026 -> cells 0..64, fits u8 each. *0.0625f is exact (pow2).
        int cxi = (int)(x * 0.0625f);
        int cyi = (int)(y * 0.0625f);
        cell[i] = (unsigned short)(cxi | (cyi << 8));
        ex[i] = 0.f;
        ey[i] = 0.f;
    }
    if (i == 0) out[0] = 0.f;   // d_out poisoned once by harness; re-init every call
}

__global__ void pairs_kernel(const int* __restrict__ src,
                             const int* __restrict__ dst,
                             const unsigned short* __restrict__ cell,
                             const float* __restrict__ cx,
                             const float* __restrict__ cy,
                             float* __restrict__ ex, float* __restrict__ ey,
                             int E) {
    int t = blockIdx.x * blockDim.x + threadIdx.x;
    int base = t * PPT;
    if (base >= E) return;
    // streaming index loads: non-temporal so they don't evict the 2MB cell table from L2
    int4v s0 = __builtin_nontemporal_load(reinterpret_cast<const int4v*>(src + base));
    int4v s1 = __builtin_nontemporal_load(reinterpret_cast<const int4v*>(src + base + 4));
    int4v d0 = __builtin_nontemporal_load(reinterpret_cast<const int4v*>(dst + base));
    int4v d1 = __builtin_nontemporal_load(reinterpret_cast<const int4v*>(dst + base + 4));
    int ss[PPT] = {s0.x, s0.y, s0.z, s0.w, s1.x, s1.y, s1.z, s1.w};
    int dd[PPT] = {d0.x, d0.y, d0.z, d0.w, d1.x, d1.y, d1.z, d1.w};
    // issue all 16 cell gathers before evaluating anything (max MLP per wave)
    int cs[PPT], cd[PPT];
#pragma unroll
    for (int k = 0; k < PPT; ++k) { cs[k] = cell[ss[k]]; cd[k] = cell[dd[k]]; }
#pragma unroll
    for (int k = 0; k < PPT; ++k) {
        int dxc = (cs[k] & 0xff) - (cd[k] & 0xff);
        int dyc = (cs[k] >> 8) - (cd[k] >> 8);
        // pass iff celldiff in {-1,0,1} for both dims (~0.2% of pairs)
        if ((unsigned)(dxc + 1) <= 2u && (unsigned)(dyc + 1) <= 2u) {
            int s = ss[k], d = dd[k];
            float dx = cx[s] - cx[d];
            float dy = cy[s] - cy[d];
            if (fabsf(dx) < THR && fabsf(dy) < THR) {
                float inv = 0.5f / (dx * dx + dy * dy + 0.01f);
                float fx = dx * inv;
                float fy = dy * inv;
                atomicAdd(&ex[s],  fx);
                atomicAdd(&ex[d], -fx);
                atomicAdd(&ey[s],  fy);
                atomicAdd(&ey[d], -fy);
            }
        }
    }
}

__global__ void reduce_kernel(const float* __restrict__ v,  // ex then ey, contiguous 2N
                              float* __restrict__ out, int n4) {
    int t = blockIdx.x * blockDim.x + threadIdx.x;
    int stride = gridDim.x * blockDim.x;
    float sum = 0.f;
    for (int i = t; i < n4; i += stride) {
        float4 a = reinterpret_cast<const float4*>(v)[i];
        sum += fabsf(a.x) + fabsf(a.y) + fabsf(a.z) + fabsf(a.w);
    }
#pragma unroll
    for (int off = 32; off > 0; off >>= 1)
        sum += __shfl_down(sum, off, 64);
    __shared__ float ss[4];
    int wid = threadIdx.x >> 6;
    if ((threadIdx.x & 63) == 0) ss[wid] = sum;
    __syncthreads();
    if (threadIdx.x == 0)
        atomicAdd(out, ss[0] + ss[1] + ss[2] + ss[3]);
}

extern "C" void kernel_launch(void* const* d_in, const int* in_sizes, int n_in,
                              void* d_out, int out_size, void* d_ws, size_t ws_size,
                              hipStream_t stream) {
    const float* pos = (const float*)d_in[0];
    const float* nsx = (const float*)d_in[1];
    const float* nsy = (const float*)d_in[2];
    const int*   src = (const int*)d_in[3];
    const int*   dst = (const int*)d_in[4];
    float* out = (float*)d_out;
    const int E = in_sizes[3];

    float* cx = (float*)d_ws;                       // [N] f32
    float* cy = cx + N_NODES;                       // [N]
    float* ex = cy + N_NODES;                       // [N]
    float* ey = ex + N_NODES;                       // [N]  (ex,ey contiguous)
    unsigned short* cell = (unsigned short*)(ey + N_NODES);  // [N] u16 = 2MB

    centers_kernel<<<(N_NODES + 255) / 256, 256, 0, stream>>>(
        pos, nsx, nsy, cx, cy, cell, ex, ey, out);

    int nthreads = E / PPT;   // E = 16777216, divisible by PPT
    pairs_kernel<<<(nthreads + 255) / 256, 256, 0, stream>>>(
        src, dst, cell, cx, cy, ex, ey, E);

    int n4 = (2 * N_NODES) / 4;
    reduce_kernel<<<2048, 256, 0, stream>>>(ex, out, n4);
}